// Round 1
// baseline (57.458 us; speedup 1.0000x reference)
//
#include <hip/hip_runtime.h>
#include <math.h>

#define BB 128      // B
#define CC 64       // C
#define EPSF 1e-6f

#define NBLK 512
#define NTHR 256
#define PAIRS_PER_BLK (BB*BB/NBLK)   // 32
#define DT_PER_THR (CC*CC/NTHR)      // 16

// ---------------- Kernel A: distance matrices ----------------
// dp[i*128+j] = sqrt(sum_k (yp[j,k]-yp[i,k]+EPS)^2)   (matches reference order)
// dt[i*64+j]  = same over y_true, i,j < 64
__global__ void dist_kernel(const float* __restrict__ yp,
                            const float* __restrict__ yt,
                            float* __restrict__ dp,
                            float* __restrict__ dt) {
    int t = blockIdx.x * blockDim.x + threadIdx.x;
    if (t < BB * BB) {
        int i = t >> 7, j = t & (BB - 1);
        const float* a = yp + i * CC;
        const float* b = yp + j * CC;
        float s = 0.f;
#pragma unroll
        for (int k = 0; k < CC; ++k) {
            float d = b[k] - a[k] + EPSF;
            s = fmaf(d, d, s);
        }
        dp[t] = sqrtf(s);
    } else if (t < BB * BB + CC * CC) {
        int t2 = t - BB * BB;
        int i = t2 >> 6, j = t2 & (CC - 1);
        const float* a = yt + i * CC;
        const float* b = yt + j * CC;
        float s = 0.f;
#pragma unroll
        for (int k = 0; k < CC; ++k) {
            float d = b[k] - a[k] + EPSF;
            s = fmaf(d, d, s);
        }
        dt[t2] = sqrtf(s);
    }
}

// ---------------- Kernel B: term1 = sum softplus(dp - dt) over masked (c,d) ----------------
__global__ void __launch_bounds__(NTHR) term1_kernel(const float* __restrict__ dp,
                                                     const float* __restrict__ dt,
                                                     double* __restrict__ acc) {
    __shared__ float dts[CC * CC];
    __shared__ double warp_s[NTHR / 64];
    int tid = threadIdx.x;

    // Stage dt in LDS; diagonal -> 1e30 so stable softplus yields exactly 0 (mask w/o branch)
    for (int k = tid; k < CC * CC; k += NTHR) {
        float v = dt[k];
        int c = k >> 6, d = k & (CC - 1);
        dts[k] = (c == d) ? 1e30f : v;
    }
    __syncthreads();

    double local = 0.0;
    int p0 = blockIdx.x * PAIRS_PER_BLK;
    for (int p = 0; p < PAIRS_PER_BLK; ++p) {
        float dpv = dp[p0 + p];          // uniform across block -> broadcast
        float part = 0.f;
#pragma unroll
        for (int m = 0; m < DT_PER_THR; ++m) {
            float x = dpv - dts[tid + m * NTHR];   // stride-1 LDS, conflict-free
            // stable softplus: max(x,0) + log(1 + exp(-|x|))
            float e = __expf(-fabsf(x));
            float sp = fmaxf(x, 0.f) + __logf(1.f + e);
            part += sp;
        }
        local += (double)part;
    }

    // wave (64-lane) shuffle reduction
    for (int off = 32; off > 0; off >>= 1)
        local += __shfl_down(local, off);
    if ((tid & 63) == 0) warp_s[tid >> 6] = local;
    __syncthreads();
    if (tid == 0) {
        double s = 0.0;
        for (int w = 0; w < NTHR / 64; ++w) s += warp_s[w];
        atomicAdd(acc, s);   // HW f64 global atomic on gfx950
    }
}

// ---------------- Kernel C: combine ----------------
__global__ void final_kernel(const float* __restrict__ dt,
                             const double* __restrict__ acc,
                             float* __restrict__ out) {
    __shared__ double ws2[4];
    int tid = threadIdx.x;
    double s = 0.0;
    for (int k = tid; k < CC * CC; k += 256) {
        int c = k >> 6, d = k & (CC - 1);
        if (c != d) s += (double)dt[k];
    }
    for (int off = 32; off > 0; off >>= 1)
        s += __shfl_down(s, off);
    if ((tid & 63) == 0) ws2[tid >> 6] = s;
    __syncthreads();
    if (tid == 0) {
        double sum_dt = ws2[0] + ws2[1] + ws2[2] + ws2[3];
        double term1 = *acc;
        double term2 = (double)BB * (double)BB * sum_dt;      // BETA = 1
        double loss = (term1 - term2) / ((double)BB * (CC - 1) * (CC - 1));
        out[0] = (float)loss;
    }
}

extern "C" void kernel_launch(void* const* d_in, const int* in_sizes, int n_in,
                              void* d_out, int out_size, void* d_ws, size_t ws_size,
                              hipStream_t stream) {
    const float* yp = (const float*)d_in[0];
    const float* yt = (const float*)d_in[1];

    float* dp = (float*)d_ws;                       // 16384 floats
    float* dt = dp + BB * BB;                       // 4096 floats
    double* acc = (double*)((char*)d_ws + (size_t)(BB * BB + CC * CC) * sizeof(float)); // 8B aligned

    // workspace is poisoned once and never re-poisoned between replays: zero the accumulator every call
    hipMemsetAsync(acc, 0, sizeof(double), stream);

    int totalA = BB * BB + CC * CC;                 // 20480
    dist_kernel<<<(totalA + 255) / 256, 256, 0, stream>>>(yp, yt, dp, dt);
    term1_kernel<<<NBLK, NTHR, 0, stream>>>(dp, dt, acc);
    final_kernel<<<1, 256, 0, stream>>>(dt, acc, (float*)d_out);
}